// Round 12
// baseline (924.144 us; speedup 1.0000x reference)
//
#include <hip/hip_runtime.h>
#include <hip/hip_bf16.h>
#include <stdint.h>

#define B_SZ  16
#define S_SZ  2048
#define D_SZ  1024
#define FF_SZ 4096
#define DT_SZ 512

typedef __bf16 bf16x8 __attribute__((ext_vector_type(8)));
typedef float  f32x16 __attribute__((ext_vector_type(16)));
typedef short  short8 __attribute__((ext_vector_type(8)));

__device__ __forceinline__ short f2bf(float x) {
    union { float f; uint32_t u; } v; v.f = x;
    uint32_t r = (v.u + 0x7fffu + ((v.u >> 16) & 1u)) >> 16;  // RNE
    return (short)(uint16_t)r;
}

// ---------------- cast f32 -> bf16, 8 elems/thread ----------------
__global__ void cast_x_kernel(const float* __restrict__ src, short* __restrict__ dst, int n8) {
    int i = blockIdx.x * 256 + threadIdx.x;
    if (i >= n8) return;
    const float4* s4 = reinterpret_cast<const float4*>(src);
    float4 a = s4[2 * i], b = s4[2 * i + 1];
    short8 v;
    v[0] = f2bf(a.x); v[1] = f2bf(a.y); v[2] = f2bf(a.z); v[3] = f2bf(a.w);
    v[4] = f2bf(b.x); v[5] = f2bf(b.y); v[6] = f2bf(b.z); v[7] = f2bf(b.w);
    reinterpret_cast<short8*>(dst)[i] = v;
}

// ---------------- transpose + cast: src f32 [R][C] -> dst bf16 [C][R] ----------------
__global__ void transpose_cast_kernel(const float* __restrict__ src, short* __restrict__ dst,
                                      int R, int C) {
    __shared__ float tile[32][33];
    int c0 = blockIdx.x * 32, r0 = blockIdx.y * 32;
    int tx = threadIdx.x, ty = threadIdx.y;   // 32 x 8
#pragma unroll
    for (int i = 0; i < 32; i += 8)
        tile[ty + i][tx] = src[(size_t)(r0 + ty + i) * C + (c0 + tx)];
    __syncthreads();
#pragma unroll
    for (int i = 0; i < 32; i += 8)
        dst[(size_t)(c0 + ty + i) * R + (r0 + tx)] = f2bf(tile[tx][ty + i]);
}

// =====================================================================
// 256x256-tile bf16 GEMM: C = A(MxK) * Bt(NxK)^T
// 8 waves (2M x 4N), per-wave 128x64 via 4x2 fragments of 32x32x16.
// B NEVER TOUCHES LDS: each wave loads its B fragments global->VGPR
// (L2-hot weights), double-buffered (bA/bB), prefetched one K-step
// ahead. Only A is staged in LDS (2 x 32KB double buffer) -> LDS pipe
// work per step drops ~55% and only ONE barrier per K-step is needed.
// A ds_reads are unfenced after the prefetch block: compiler-counted
// lgkm waits drain them under the MFMA stream (B already in regs).
// XOR-swizzled A rows (128B): phys = r*128 + (((2ks+lh) ^ (r&7))<<4).
// =====================================================================

#define GLOAD(srcp, dstofs)                                                   \
    __builtin_amdgcn_global_load_lds(                                         \
        (__attribute__((address_space(1))) void*)(srcp),                      \
        (__attribute__((address_space(3))) void*)(ldsb + (dstofs)), 16, 0, 0)

// One K-step of 64: A slot S (literal), B current regs BCUR, B next BNXT.
// Entry: vmcnt(0)+barrier (everything outstanding is THIS step's data,
// issued a full step ago). Then issue next step's B-reg loads + A stage,
// then compute (compiler pipelines A reads under MFMAs).
#define STEP(S, BCUR, BNXT, T, STG) do {                                                    \
    asm volatile("s_waitcnt vmcnt(0)" ::: "memory");                                        \
    __builtin_amdgcn_s_barrier();                                                           \
    if (STG) {                                                                              \
        _Pragma("unroll")                                                                   \
        for (int ni = 0; ni < 2; ++ni)                                                      \
            _Pragma("unroll")                                                               \
            for (int ks = 0; ks < 4; ++ks)                                                  \
                BNXT[ni * 4 + ks] = *reinterpret_cast<const bf16x8*>(                       \
                    pB[ni] + (size_t)((T) + 1) * 64 + ks * 16);                             \
        _Pragma("unroll")                                                                   \
        for (int j = 0; j < 4; ++j)                                                         \
            GLOAD(gA[j] + (size_t)((T) + 1) * 64,                                           \
                  ((S) ^ 1) * 32768 + j * 8192 + tid * 16);                                 \
    }                                                                                       \
    __builtin_amdgcn_sched_barrier(0);                                                      \
    _Pragma("unroll")                                                                       \
    for (int ks = 0; ks < 4; ++ks) {                                                        \
        bf16x8 a[4];                                                                        \
        _Pragma("unroll")                                                                   \
        for (int mi = 0; mi < 4; ++mi)                                                      \
            a[mi] = *reinterpret_cast<const bf16x8*>(                                       \
                ldsb + (S) * 32768 + (offA0[mi] ^ (ks << 5)));                              \
        __builtin_amdgcn_s_setprio(1);                                                      \
        _Pragma("unroll")                                                                   \
        for (int mi = 0; mi < 4; ++mi)                                                      \
            _Pragma("unroll")                                                               \
            for (int ni = 0; ni < 2; ++ni)                                                  \
                acc[mi][ni] = __builtin_amdgcn_mfma_f32_32x32x16_bf16(                      \
                    a[mi], BCUR[ni * 4 + ks], acc[mi][ni], 0, 0, 0);                        \
        __builtin_amdgcn_s_setprio(0);                                                      \
    }                                                                                       \
} while (0)

template <bool GELU_BF16>
__global__ __launch_bounds__(512, 2)
void gemm256_kernel(const short* __restrict__ A, const short* __restrict__ Bt,
                    void* __restrict__ Cout, int M, int N, int K) {
    __shared__ char lds2[2][32768];   // A double buffer only: [256 rows][128B]
    char* ldsb = &lds2[0][0];

    const int tid = threadIdx.x;
    const int w   = tid >> 6;
    const int l   = tid & 63;
    const int wm  = w >> 2;        // 0..1
    const int wn  = w & 3;         // 0..3
    const int l31 = l & 31;
    const int lh  = l >> 5;        // 0..1

    // XCD-bijective block swizzle; bn-fast so consecutive blocks share the A-tile
    const int nwg = gridDim.x;
    int swzw = blockIdx.x;
    if ((nwg & 7) == 0) swzw = (swzw & 7) * (nwg >> 3) + (swzw >> 3);
    const int NB = N >> 8;
    const int bm = swzw / NB, bn = swzw % NB;
    const int m0 = bm << 8, n0 = bn << 8;

    // ---- swizzled A ds_read offsets for ks=0 (ks -> off ^ (ks<<5)) ----
    int offA0[4];
#pragma unroll
    for (int mi = 0; mi < 4; ++mi) {
        const int r = wm * 128 + mi * 32 + l31;
        offA0[mi] = r * 128 + ((lh ^ (r & 7)) << 4);
    }

    // ---- A staging sources (inverse-swizzled global, linear LDS dest) ----
    const short* gA[4];
#pragma unroll
    for (int j = 0; j < 4; ++j) {
        const int X = j * 8192 + tid * 16;
        const int P = X ^ (((X >> 7) & 7) << 4);
        const int r = P >> 7, c = (P & 127) >> 1;
        gA[j] = A + (size_t)(m0 + r) * K + c;
    }

    // ---- B fragment bases (direct global, per-lane) ----
    const short* pB[2];
#pragma unroll
    for (int ni = 0; ni < 2; ++ni)
        pB[ni] = Bt + (size_t)(n0 + wn * 64 + ni * 32 + l31) * K + lh * 8;

    f32x16 acc[4][2];
#pragma unroll
    for (int mi = 0; mi < 4; ++mi)
#pragma unroll
        for (int ni = 0; ni < 2; ++ni)
            acc[mi][ni] = (f32x16)(0.f);

    bf16x8 bA[8], bB[8];
    const int NT = K >> 6;            // K-steps of 64 (16 or 64 here, even)

    // prologue: B regs for step 0 + A stage of step 0 into slot 0
#pragma unroll
    for (int ni = 0; ni < 2; ++ni)
#pragma unroll
        for (int ks = 0; ks < 4; ++ks)
            bA[ni * 4 + ks] = *reinterpret_cast<const bf16x8*>(pB[ni] + ks * 16);
#pragma unroll
    for (int j = 0; j < 4; ++j)
        GLOAD(gA[j], j * 8192 + tid * 16);

    for (int t = 0; t < NT - 2; t += 2) {
        STEP(0, bA, bB, t, 1);
        STEP(1, bB, bA, t + 1, 1);
    }
    STEP(0, bA, bB, NT - 2, 1);
    STEP(1, bB, bA, NT - 1, 0);

    // epilogue — 32x32 D layout (m74/m101, r11-verified): col = lane&31,
    // row = (reg&3) + 8*(reg>>2) + 4*(lane>>5)
    const int col0 = n0 + wn * 64 + l31;
    if constexpr (GELU_BF16) {
        short* C = reinterpret_cast<short*>(Cout);
#pragma unroll
        for (int mi = 0; mi < 4; ++mi) {
            const int rb = m0 + wm * 128 + mi * 32 + 4 * lh;
#pragma unroll
            for (int ni = 0; ni < 2; ++ni)
#pragma unroll
                for (int reg = 0; reg < 16; ++reg) {
                    const int row = rb + (reg & 3) + 8 * (reg >> 2);
                    float x = acc[mi][ni][reg];
                    float u = 0.7978845608028654f * (x + 0.044715f * x * x * x);
                    float g = x / (1.f + __expf(-2.f * u));
                    C[(size_t)row * N + col0 + ni * 32] = f2bf(g);
                }
        }
    } else {
        float* C = reinterpret_cast<float*>(Cout);
#pragma unroll
        for (int mi = 0; mi < 4; ++mi) {
            const int rb = m0 + wm * 128 + mi * 32 + 4 * lh;
#pragma unroll
            for (int ni = 0; ni < 2; ++ni)
#pragma unroll
                for (int reg = 0; reg < 16; ++reg) {
                    const int row = rb + (reg & 3) + 8 * (reg >> 2);
                    C[(size_t)row * N + col0 + ni * 32] = acc[mi][ni][reg];
                }
        }
    }
}

// ---------------- intervention: out[b, eot[b], 0:512] = row[0:512] @ Wrot @ Winv ----------------
__global__ void intervention_kernel(const float* __restrict__ Wrot, const float* __restrict__ Winv,
                                    const int* __restrict__ eot, float* __restrict__ out) {
    __shared__ float tgt[DT_SZ];
    __shared__ float tmp[DT_SZ];
    const int b = blockIdx.x;
    const int j = threadIdx.x;
    float* row = out + ((size_t)b * S_SZ + eot[b]) * D_SZ;
    tgt[j] = row[j];                      // ST=0 slice
    __syncthreads();
    float s = 0.f;
#pragma unroll 8
    for (int i = 0; i < DT_SZ; ++i) s = fmaf(tgt[i], Wrot[(size_t)i * DT_SZ + j], s);
    tmp[j] = s;
    __syncthreads();
    float s2 = 0.f;
#pragma unroll 8
    for (int i = 0; i < DT_SZ; ++i) s2 = fmaf(tmp[i], Winv[(size_t)i * DT_SZ + j], s2);
    row[j] = s2;
}

extern "C" void kernel_launch(void* const* d_in, const int* in_sizes, int n_in,
                              void* d_out, int out_size, void* d_ws, size_t ws_size,
                              hipStream_t stream) {
    const float* hidden = (const float*)d_in[0];
    const float* W1     = (const float*)d_in[1];
    const float* W2     = (const float*)d_in[2];
    const float* Wrot   = (const float*)d_in[3];
    const float* Winv   = (const float*)d_in[4];
    const int*   eot    = (const int*)d_in[5];
    float* out = (float*)d_out;

    const int M = B_SZ * S_SZ;   // 32768

    // ws layout: W1t (FF x D bf16) | W2t (D x FF bf16) | Xbf chunk | C1 chunk
    short* W1t = (short*)d_ws;
    short* W2t = W1t + (size_t)FF_SZ * D_SZ;
    short* Xbf = W2t + (size_t)FF_SZ * D_SZ;
    const size_t fixed_bytes = 2ull * (size_t)FF_SZ * D_SZ * sizeof(short);  // 16 MiB
    const size_t per_row = (size_t)D_SZ * 2 + (size_t)FF_SZ * 2;             // 10240 B
    size_t rem = ws_size > fixed_bytes ? ws_size - fixed_bytes : 0;
    int Mc = (int)(rem / per_row);
    Mc = (Mc / 512) * 512;       // keeps every grid a multiple of 8
    if (Mc < 512) Mc = 512;
    if (Mc > M) Mc = M;
    short* C1 = Xbf + (size_t)Mc * D_SZ;

    transpose_cast_kernel<<<dim3(FF_SZ / 32, D_SZ / 32), dim3(32, 8), 0, stream>>>(W1, W1t, D_SZ, FF_SZ);
    transpose_cast_kernel<<<dim3(D_SZ / 32, FF_SZ / 32), dim3(32, 8), 0, stream>>>(W2, W2t, FF_SZ, D_SZ);

    for (int ms = 0; ms < M; ms += Mc) {
        const int mc = (M - ms < Mc) ? (M - ms) : Mc;   // multiple of 512
        const int n8 = mc * D_SZ / 8;
        cast_x_kernel<<<(n8 + 255) / 256, 256, 0, stream>>>(hidden + (size_t)ms * D_SZ, Xbf, n8);
        gemm256_kernel<true ><<<dim3((mc / 256) * (FF_SZ / 256)), 512, 0, stream>>>(
            Xbf, W1t, C1, mc, FF_SZ, D_SZ);
        gemm256_kernel<false><<<dim3((mc / 256) * (D_SZ / 256)), 512, 0, stream>>>(
            C1, W2t, out + (size_t)ms * D_SZ, mc, D_SZ, FF_SZ);
    }
    intervention_kernel<<<B_SZ, DT_SZ, 0, stream>>>(Wrot, Winv, eot, out);
}

// Round 13
// 732.326 us; speedup vs baseline: 1.2619x; 1.2619x over previous
//
#include <hip/hip_runtime.h>
#include <hip/hip_bf16.h>
#include <stdint.h>

#define B_SZ  16
#define S_SZ  2048
#define D_SZ  1024
#define FF_SZ 4096
#define DT_SZ 512

typedef __bf16 bf16x8 __attribute__((ext_vector_type(8)));
typedef float  f32x4  __attribute__((ext_vector_type(4)));
typedef short  short8 __attribute__((ext_vector_type(8)));

__device__ __forceinline__ short f2bf(float x) {
    union { float f; uint32_t u; } v; v.f = x;
    uint32_t r = (v.u + 0x7fffu + ((v.u >> 16) & 1u)) >> 16;  // RNE
    return (short)(uint16_t)r;
}

// ---------------- cast f32 -> bf16, 8 elems/thread ----------------
__global__ void cast_x_kernel(const float* __restrict__ src, short* __restrict__ dst, int n8) {
    int i = blockIdx.x * 256 + threadIdx.x;
    if (i >= n8) return;
    const float4* s4 = reinterpret_cast<const float4*>(src);
    float4 a = s4[2 * i], b = s4[2 * i + 1];
    short8 v;
    v[0] = f2bf(a.x); v[1] = f2bf(a.y); v[2] = f2bf(a.z); v[3] = f2bf(a.w);
    v[4] = f2bf(b.x); v[5] = f2bf(b.y); v[6] = f2bf(b.z); v[7] = f2bf(b.w);
    reinterpret_cast<short8*>(dst)[i] = v;
}

// ---------------- transpose + cast: src f32 [R][C] -> dst bf16 [C][R] ----------------
__global__ void transpose_cast_kernel(const float* __restrict__ src, short* __restrict__ dst,
                                      int R, int C) {
    __shared__ float tile[32][33];
    int c0 = blockIdx.x * 32, r0 = blockIdx.y * 32;
    int tx = threadIdx.x, ty = threadIdx.y;   // 32 x 8
#pragma unroll
    for (int i = 0; i < 32; i += 8)
        tile[ty + i][tx] = src[(size_t)(r0 + ty + i) * C + (c0 + tx)];
    __syncthreads();
#pragma unroll
    for (int i = 0; i < 32; i += 8)
        dst[(size_t)(c0 + ty + i) * R + (r0 + tx)] = f2bf(tile[tx][ty + i]);
}

// =====================================================================
// 128x128-tile bf16 GEMM: C = A(MxK) * Bt(NxK)^T — m97-simple structure
// tuned for CROSS-BLOCK overlap (the m114/m97 mechanism):
//   * 4 waves (2x2), per-wave 64x64 via 4x4 acc of 16x16x32 MFMA
//   * BK=64, SINGLE 32 KB LDS buffer, plain __syncthreads() only
//     (no inline asm: compiler emits drains; other resident blocks
//      compute during this block's stage/drain)
//   * __launch_bounds__(256,3) -> 3 blocks/CU (96 KB LDS, VGPR<=168)
//   * 2-way-free XOR swizzle (r11-verified), XCD-bijective + bn-fast
// =====================================================================

#define GLOAD(srcp, dstofs)                                                   \
    __builtin_amdgcn_global_load_lds(                                         \
        (__attribute__((address_space(1))) void*)(srcp),                      \
        (__attribute__((address_space(3))) void*)(ldsb + (dstofs)), 16, 0, 0)

template <bool GELU_BF16>
__global__ __launch_bounds__(256, 3)
void gemm128_kernel(const short* __restrict__ A, const short* __restrict__ Bt,
                    void* __restrict__ Cout, int M, int N, int K) {
    __shared__ char lds[32768];    // A[128 rows x 128B] @0, B @16384
    char* ldsb = &lds[0];

    const int tid = threadIdx.x;
    const int w   = tid >> 6;      // 0..3
    const int l   = tid & 63;
    const int wm  = w >> 1;        // 0..1
    const int wn  = w & 1;         // 0..1
    const int kq  = l >> 4;        // 0..3
    const int l15 = l & 15;

    // XCD-bijective block swizzle; bn-fast so consecutive blocks share the A-tile
    const int nwg = gridDim.x;
    int swzw = blockIdx.x;
    if ((nwg & 7) == 0) swzw = (swzw & 7) * (nwg >> 3) + (swzw >> 3);
    const int NB = N >> 7;
    const int bm = swzw / NB, bn = swzw % NB;
    const int m0 = bm << 7, n0 = bn << 7;

    // ---- swizzled ds_read byte offsets, ks=0 (ks=1: off ^ 0x40) ----
    // logical slot = ks*4 + kq (16B units in a 128B row); phys slot = slot ^ (r&7)
    int offA[4], offB[4];
#pragma unroll
    for (int mi = 0; mi < 4; ++mi) {
        const int r = wm * 64 + mi * 16 + l15;
        offA[mi] = r * 128 + ((kq ^ (r & 7)) << 4);
    }
#pragma unroll
    for (int ni = 0; ni < 4; ++ni) {
        const int r = wn * 64 + ni * 16 + l15;
        offB[ni] = 16384 + r * 128 + ((kq ^ (r & 7)) << 4);
    }

    // ---- staging sources (inverse-swizzled global, linear LDS dest) ----
    // per-operand 16KB: X = j*4096 + tid*16 ; P = X ^ (((X>>7)&7)<<4) ;
    // row = P>>7 (0..127), col elems = (P&127)>>1
    const short *gA[4], *gB[4];
#pragma unroll
    for (int j = 0; j < 4; ++j) {
        const int X = j * 4096 + tid * 16;
        const int P = X ^ (((X >> 7) & 7) << 4);
        const int r = P >> 7, c = (P & 127) >> 1;
        gA[j] = A  + (size_t)(m0 + r) * K + c;
        gB[j] = Bt + (size_t)(n0 + r) * K + c;
    }

    f32x4 acc[4][4];
#pragma unroll
    for (int mi = 0; mi < 4; ++mi)
#pragma unroll
        for (int ni = 0; ni < 4; ++ni)
            acc[mi][ni] = (f32x4){0.f, 0.f, 0.f, 0.f};

    const int NT = K >> 6;         // K-steps of 64 (16 or 64 here)

    for (int t = 0; t < NT; ++t) {
        __syncthreads();           // WAR: previous step's reads done
#pragma unroll
        for (int j = 0; j < 4; ++j) {
            GLOAD(gA[j] + (size_t)t * 64,         j * 4096 + tid * 16);
            GLOAD(gB[j] + (size_t)t * 64, 16384 + j * 4096 + tid * 16);
        }
        __syncthreads();           // compiler drains vmcnt before barrier
#pragma unroll
        for (int ks = 0; ks < 2; ++ks) {
            bf16x8 a[4], b[4];
#pragma unroll
            for (int mi = 0; mi < 4; ++mi)
                a[mi] = *reinterpret_cast<const bf16x8*>(ldsb + (offA[mi] ^ (ks << 6)));
#pragma unroll
            for (int ni = 0; ni < 4; ++ni)
                b[ni] = *reinterpret_cast<const bf16x8*>(ldsb + (offB[ni] ^ (ks << 6)));
#pragma unroll
            for (int mi = 0; mi < 4; ++mi)
#pragma unroll
                for (int ni = 0; ni < 4; ++ni)
                    acc[mi][ni] = __builtin_amdgcn_mfma_f32_16x16x32_bf16(
                        a[mi], b[ni], acc[mi][ni], 0, 0, 0);
        }
    }

    // epilogue — D layout (m89): col = lane&15, row = (lane>>4)*4 + reg
    const int row_base = m0 + wm * 64 + kq * 4;
    const int col_base = n0 + wn * 64 + l15;
    if constexpr (GELU_BF16) {
        short* C = reinterpret_cast<short*>(Cout);
#pragma unroll
        for (int mi = 0; mi < 4; ++mi)
#pragma unroll
            for (int r = 0; r < 4; ++r) {
                const size_t ro = (size_t)(row_base + mi * 16 + r) * N;
#pragma unroll
                for (int ni = 0; ni < 4; ++ni) {
                    float x = acc[mi][ni][r];
                    float u = 0.7978845608028654f * (x + 0.044715f * x * x * x);
                    float g = x / (1.f + __expf(-2.f * u));
                    C[ro + col_base + ni * 16] = f2bf(g);
                }
            }
    } else {
        float* C = reinterpret_cast<float*>(Cout);
#pragma unroll
        for (int mi = 0; mi < 4; ++mi)
#pragma unroll
            for (int r = 0; r < 4; ++r) {
                const size_t ro = (size_t)(row_base + mi * 16 + r) * N;
#pragma unroll
                for (int ni = 0; ni < 4; ++ni)
                    C[ro + col_base + ni * 16] = acc[mi][ni][r];
            }
    }
}

// ---------------- intervention: out[b, eot[b], 0:512] = row[0:512] @ Wrot @ Winv ----------------
__global__ void intervention_kernel(const float* __restrict__ Wrot, const float* __restrict__ Winv,
                                    const int* __restrict__ eot, float* __restrict__ out) {
    __shared__ float tgt[DT_SZ];
    __shared__ float tmp[DT_SZ];
    const int b = blockIdx.x;
    const int j = threadIdx.x;
    float* row = out + ((size_t)b * S_SZ + eot[b]) * D_SZ;
    tgt[j] = row[j];                      // ST=0 slice
    __syncthreads();
    float s = 0.f;
#pragma unroll 8
    for (int i = 0; i < DT_SZ; ++i) s = fmaf(tgt[i], Wrot[(size_t)i * DT_SZ + j], s);
    tmp[j] = s;
    __syncthreads();
    float s2 = 0.f;
#pragma unroll 8
    for (int i = 0; i < DT_SZ; ++i) s2 = fmaf(tmp[i], Winv[(size_t)i * DT_SZ + j], s2);
    row[j] = s2;
}

extern "C" void kernel_launch(void* const* d_in, const int* in_sizes, int n_in,
                              void* d_out, int out_size, void* d_ws, size_t ws_size,
                              hipStream_t stream) {
    const float* hidden = (const float*)d_in[0];
    const float* W1     = (const float*)d_in[1];
    const float* W2     = (const float*)d_in[2];
    const float* Wrot   = (const float*)d_in[3];
    const float* Winv   = (const float*)d_in[4];
    const int*   eot    = (const int*)d_in[5];
    float* out = (float*)d_out;

    const int M = B_SZ * S_SZ;   // 32768

    // ws layout: W1t (FF x D bf16) | W2t (D x FF bf16) | Xbf chunk | C1 chunk
    short* W1t = (short*)d_ws;
    short* W2t = W1t + (size_t)FF_SZ * D_SZ;
    short* Xbf = W2t + (size_t)FF_SZ * D_SZ;
    const size_t fixed_bytes = 2ull * (size_t)FF_SZ * D_SZ * sizeof(short);  // 16 MiB
    const size_t per_row = (size_t)D_SZ * 2 + (size_t)FF_SZ * 2;             // 10240 B
    size_t rem = ws_size > fixed_bytes ? ws_size - fixed_bytes : 0;
    int Mc = (int)(rem / per_row);
    Mc = (Mc / 512) * 512;       // keeps every grid a multiple of 8
    if (Mc < 512) Mc = 512;
    if (Mc > M) Mc = M;
    short* C1 = Xbf + (size_t)Mc * D_SZ;

    transpose_cast_kernel<<<dim3(FF_SZ / 32, D_SZ / 32), dim3(32, 8), 0, stream>>>(W1, W1t, D_SZ, FF_SZ);
    transpose_cast_kernel<<<dim3(D_SZ / 32, FF_SZ / 32), dim3(32, 8), 0, stream>>>(W2, W2t, FF_SZ, D_SZ);

    for (int ms = 0; ms < M; ms += Mc) {
        const int mc = (M - ms < Mc) ? (M - ms) : Mc;   // multiple of 512
        const int n8 = mc * D_SZ / 8;
        cast_x_kernel<<<(n8 + 255) / 256, 256, 0, stream>>>(hidden + (size_t)ms * D_SZ, Xbf, n8);
        gemm128_kernel<true ><<<dim3((mc / 128) * (FF_SZ / 128)), 256, 0, stream>>>(
            Xbf, W1t, C1, mc, FF_SZ, D_SZ);
        gemm128_kernel<false><<<dim3((mc / 128) * (D_SZ / 128)), 256, 0, stream>>>(
            C1, W2t, out + (size_t)ms * D_SZ, mc, D_SZ, FF_SZ);
    }
    intervention_kernel<<<B_SZ, DT_SZ, 0, stream>>>(Wrot, Winv, eot, out);
}

// Round 14
// 731.823 us; speedup vs baseline: 1.2628x; 1.0007x over previous
//
#include <hip/hip_runtime.h>
#include <hip/hip_bf16.h>
#include <stdint.h>

#define B_SZ  16
#define S_SZ  2048
#define D_SZ  1024
#define FF_SZ 4096
#define DT_SZ 512

typedef __bf16 bf16x8 __attribute__((ext_vector_type(8)));
typedef float  f32x4  __attribute__((ext_vector_type(4)));
typedef short  short8 __attribute__((ext_vector_type(8)));

__device__ __forceinline__ short f2bf(float x) {
    union { float f; uint32_t u; } v; v.f = x;
    uint32_t r = (v.u + 0x7fffu + ((v.u >> 16) & 1u)) >> 16;  // RNE
    return (short)(uint16_t)r;
}

// ---------------- cast f32 -> bf16, 8 elems/thread ----------------
__global__ void cast_x_kernel(const float* __restrict__ src, short* __restrict__ dst, int n8) {
    int i = blockIdx.x * 256 + threadIdx.x;
    if (i >= n8) return;
    const float4* s4 = reinterpret_cast<const float4*>(src);
    float4 a = s4[2 * i], b = s4[2 * i + 1];
    short8 v;
    v[0] = f2bf(a.x); v[1] = f2bf(a.y); v[2] = f2bf(a.z); v[3] = f2bf(a.w);
    v[4] = f2bf(b.x); v[5] = f2bf(b.y); v[6] = f2bf(b.z); v[7] = f2bf(b.w);
    reinterpret_cast<short8*>(dst)[i] = v;
}

// ---------------- transpose + cast: src f32 [R][C] -> dst bf16 [C][R] ----------------
__global__ void transpose_cast_kernel(const float* __restrict__ src, short* __restrict__ dst,
                                      int R, int C) {
    __shared__ float tile[32][33];
    int c0 = blockIdx.x * 32, r0 = blockIdx.y * 32;
    int tx = threadIdx.x, ty = threadIdx.y;   // 32 x 8
#pragma unroll
    for (int i = 0; i < 32; i += 8)
        tile[ty + i][tx] = src[(size_t)(r0 + ty + i) * C + (c0 + tx)];
    __syncthreads();
#pragma unroll
    for (int i = 0; i < 32; i += 8)
        dst[(size_t)(c0 + ty + i) * R + (r0 + tx)] = f2bf(tile[tx][ty + i]);
}

// =====================================================================
// 128x128-tile bf16 GEMM: C = A(MxK) * Bt(NxK)^T — m97-simple structure
// tuned for CROSS-BLOCK overlap (the m114/m97 mechanism):
//   * 4 waves (2x2), per-wave 64x64 via 4x4 acc of 16x16x32 MFMA
//   * BK=64, SINGLE 32 KB LDS buffer, plain __syncthreads() only
//   * __launch_bounds__(256,4) -> 4 blocks/CU (128 KB LDS, 128 regs/wave)
//     r13 measured 3 blocks/CU: LDS pipe 66% busy, MFMA 41% — one more
//     resident block raises overlap of the two pipes.
//   * 2-way-free XOR swizzle (r11-verified), XCD-bijective + bn-fast
// =====================================================================

#define GLOAD(srcp, dstofs)                                                   \
    __builtin_amdgcn_global_load_lds(                                         \
        (__attribute__((address_space(1))) void*)(srcp),                      \
        (__attribute__((address_space(3))) void*)(ldsb + (dstofs)), 16, 0, 0)

template <bool GELU_BF16>
__global__ __launch_bounds__(256, 4)
void gemm128_kernel(const short* __restrict__ A, const short* __restrict__ Bt,
                    void* __restrict__ Cout, int M, int N, int K) {
    __shared__ char lds[32768];    // A[128 rows x 128B] @0, B @16384
    char* ldsb = &lds[0];

    const int tid = threadIdx.x;
    const int w   = tid >> 6;      // 0..3
    const int l   = tid & 63;
    const int wm  = w >> 1;        // 0..1
    const int wn  = w & 1;         // 0..1
    const int kq  = l >> 4;        // 0..3
    const int l15 = l & 15;

    // XCD-bijective block swizzle; bn-fast so consecutive blocks share the A-tile
    const int nwg = gridDim.x;
    int swzw = blockIdx.x;
    if ((nwg & 7) == 0) swzw = (swzw & 7) * (nwg >> 3) + (swzw >> 3);
    const int NB = N >> 7;
    const int bm = swzw / NB, bn = swzw % NB;
    const int m0 = bm << 7, n0 = bn << 7;

    // ---- swizzled ds_read byte offsets, ks=0 (ks=1: off ^ 0x40) ----
    int offA[4], offB[4];
#pragma unroll
    for (int mi = 0; mi < 4; ++mi) {
        const int r = wm * 64 + mi * 16 + l15;
        offA[mi] = r * 128 + ((kq ^ (r & 7)) << 4);
    }
#pragma unroll
    for (int ni = 0; ni < 4; ++ni) {
        const int r = wn * 64 + ni * 16 + l15;
        offB[ni] = 16384 + r * 128 + ((kq ^ (r & 7)) << 4);
    }

    // ---- staging sources (inverse-swizzled global, linear LDS dest) ----
    const short *gA[4], *gB[4];
#pragma unroll
    for (int j = 0; j < 4; ++j) {
        const int X = j * 4096 + tid * 16;
        const int P = X ^ (((X >> 7) & 7) << 4);
        const int r = P >> 7, c = (P & 127) >> 1;
        gA[j] = A  + (size_t)(m0 + r) * K + c;
        gB[j] = Bt + (size_t)(n0 + r) * K + c;
    }

    f32x4 acc[4][4];
#pragma unroll
    for (int mi = 0; mi < 4; ++mi)
#pragma unroll
        for (int ni = 0; ni < 4; ++ni)
            acc[mi][ni] = (f32x4){0.f, 0.f, 0.f, 0.f};

    const int NT = K >> 6;         // K-steps of 64 (16 or 64 here)

    for (int t = 0; t < NT; ++t) {
        __syncthreads();           // WAR: previous step's reads done
#pragma unroll
        for (int j = 0; j < 4; ++j) {
            GLOAD(gA[j] + (size_t)t * 64,         j * 4096 + tid * 16);
            GLOAD(gB[j] + (size_t)t * 64, 16384 + j * 4096 + tid * 16);
        }
        __syncthreads();           // compiler drains vmcnt before barrier
#pragma unroll
        for (int ks = 0; ks < 2; ++ks) {
            bf16x8 a[4], b[4];
#pragma unroll
            for (int mi = 0; mi < 4; ++mi)
                a[mi] = *reinterpret_cast<const bf16x8*>(ldsb + (offA[mi] ^ (ks << 6)));
#pragma unroll
            for (int ni = 0; ni < 4; ++ni)
                b[ni] = *reinterpret_cast<const bf16x8*>(ldsb + (offB[ni] ^ (ks << 6)));
#pragma unroll
            for (int mi = 0; mi < 4; ++mi)
#pragma unroll
                for (int ni = 0; ni < 4; ++ni)
                    acc[mi][ni] = __builtin_amdgcn_mfma_f32_16x16x32_bf16(
                        a[mi], b[ni], acc[mi][ni], 0, 0, 0);
        }
    }

    // epilogue — D layout (m89): col = lane&15, row = (lane>>4)*4 + reg
    const int row_base = m0 + wm * 64 + kq * 4;
    const int col_base = n0 + wn * 64 + l15;
    if constexpr (GELU_BF16) {
        short* C = reinterpret_cast<short*>(Cout);
#pragma unroll
        for (int mi = 0; mi < 4; ++mi)
#pragma unroll
            for (int r = 0; r < 4; ++r) {
                const size_t ro = (size_t)(row_base + mi * 16 + r) * N;
#pragma unroll
                for (int ni = 0; ni < 4; ++ni) {
                    float x = acc[mi][ni][r];
                    float u = 0.7978845608028654f * (x + 0.044715f * x * x * x);
                    float g = x / (1.f + __expf(-2.f * u));
                    C[ro + col_base + ni * 16] = f2bf(g);
                }
            }
    } else {
        float* C = reinterpret_cast<float*>(Cout);
#pragma unroll
        for (int mi = 0; mi < 4; ++mi)
#pragma unroll
            for (int r = 0; r < 4; ++r) {
                const size_t ro = (size_t)(row_base + mi * 16 + r) * N;
#pragma unroll
                for (int ni = 0; ni < 4; ++ni)
                    C[ro + col_base + ni * 16] = acc[mi][ni][r];
            }
    }
}

// ---------------- intervention: out[b, eot[b], 0:512] = row[0:512] @ Wrot @ Winv ----------------
__global__ void intervention_kernel(const float* __restrict__ Wrot, const float* __restrict__ Winv,
                                    const int* __restrict__ eot, float* __restrict__ out) {
    __shared__ float tgt[DT_SZ];
    __shared__ float tmp[DT_SZ];
    const int b = blockIdx.x;
    const int j = threadIdx.x;
    float* row = out + ((size_t)b * S_SZ + eot[b]) * D_SZ;
    tgt[j] = row[j];                      // ST=0 slice
    __syncthreads();
    float s = 0.f;
#pragma unroll 8
    for (int i = 0; i < DT_SZ; ++i) s = fmaf(tgt[i], Wrot[(size_t)i * DT_SZ + j], s);
    tmp[j] = s;
    __syncthreads();
    float s2 = 0.f;
#pragma unroll 8
    for (int i = 0; i < DT_SZ; ++i) s2 = fmaf(tmp[i], Winv[(size_t)i * DT_SZ + j], s2);
    row[j] = s2;
}

extern "C" void kernel_launch(void* const* d_in, const int* in_sizes, int n_in,
                              void* d_out, int out_size, void* d_ws, size_t ws_size,
                              hipStream_t stream) {
    const float* hidden = (const float*)d_in[0];
    const float* W1     = (const float*)d_in[1];
    const float* W2     = (const float*)d_in[2];
    const float* Wrot   = (const float*)d_in[3];
    const float* Winv   = (const float*)d_in[4];
    const int*   eot    = (const int*)d_in[5];
    float* out = (float*)d_out;

    const int M = B_SZ * S_SZ;   // 32768

    // ws layout: W1t (FF x D bf16) | W2t (D x FF bf16) | Xbf chunk | C1 chunk
    short* W1t = (short*)d_ws;
    short* W2t = W1t + (size_t)FF_SZ * D_SZ;
    short* Xbf = W2t + (size_t)FF_SZ * D_SZ;
    const size_t fixed_bytes = 2ull * (size_t)FF_SZ * D_SZ * sizeof(short);  // 16 MiB
    const size_t per_row = (size_t)D_SZ * 2 + (size_t)FF_SZ * 2;             // 10240 B
    size_t rem = ws_size > fixed_bytes ? ws_size - fixed_bytes : 0;
    int Mc = (int)(rem / per_row);
    Mc = (Mc / 512) * 512;       // keeps every grid a multiple of 8
    if (Mc < 512) Mc = 512;
    if (Mc > M) Mc = M;
    short* C1 = Xbf + (size_t)Mc * D_SZ;

    transpose_cast_kernel<<<dim3(FF_SZ / 32, D_SZ / 32), dim3(32, 8), 0, stream>>>(W1, W1t, D_SZ, FF_SZ);
    transpose_cast_kernel<<<dim3(D_SZ / 32, FF_SZ / 32), dim3(32, 8), 0, stream>>>(W2, W2t, FF_SZ, D_SZ);

    for (int ms = 0; ms < M; ms += Mc) {
        const int mc = (M - ms < Mc) ? (M - ms) : Mc;   // multiple of 512
        const int n8 = mc * D_SZ / 8;
        cast_x_kernel<<<(n8 + 255) / 256, 256, 0, stream>>>(hidden + (size_t)ms * D_SZ, Xbf, n8);
        gemm128_kernel<true ><<<dim3((mc / 128) * (FF_SZ / 128)), 256, 0, stream>>>(
            Xbf, W1t, C1, mc, FF_SZ, D_SZ);
        gemm128_kernel<false><<<dim3((mc / 128) * (D_SZ / 128)), 256, 0, stream>>>(
            C1, W2t, out + (size_t)ms * D_SZ, mc, D_SZ, FF_SZ);
    }
    intervention_kernel<<<B_SZ, DT_SZ, 0, stream>>>(Wrot, Winv, eot, out);
}

// Round 15
// 713.112 us; speedup vs baseline: 1.2959x; 1.0262x over previous
//
#include <hip/hip_runtime.h>
#include <hip/hip_bf16.h>
#include <stdint.h>

#define B_SZ  16
#define S_SZ  2048
#define D_SZ  1024
#define FF_SZ 4096
#define DT_SZ 512

typedef __bf16 bf16x8 __attribute__((ext_vector_type(8)));
typedef float  f32x4  __attribute__((ext_vector_type(4)));
typedef short  short8 __attribute__((ext_vector_type(8)));

__device__ __forceinline__ short f2bf(float x) {
    union { float f; uint32_t u; } v; v.f = x;
    uint32_t r = (v.u + 0x7fffu + ((v.u >> 16) & 1u)) >> 16;  // RNE
    return (short)(uint16_t)r;
}

// ---------------- cast f32 -> bf16, 8 elems/thread ----------------
__global__ void cast_x_kernel(const float* __restrict__ src, short* __restrict__ dst, int n8) {
    int i = blockIdx.x * 256 + threadIdx.x;
    if (i >= n8) return;
    const float4* s4 = reinterpret_cast<const float4*>(src);
    float4 a = s4[2 * i], b = s4[2 * i + 1];
    short8 v;
    v[0] = f2bf(a.x); v[1] = f2bf(a.y); v[2] = f2bf(a.z); v[3] = f2bf(a.w);
    v[4] = f2bf(b.x); v[5] = f2bf(b.y); v[6] = f2bf(b.z); v[7] = f2bf(b.w);
    reinterpret_cast<short8*>(dst)[i] = v;
}

// ---------------- transpose + cast: src f32 [R][C] -> dst bf16 [C][R] ----------------
__global__ void transpose_cast_kernel(const float* __restrict__ src, short* __restrict__ dst,
                                      int R, int C) {
    __shared__ float tile[32][33];
    int c0 = blockIdx.x * 32, r0 = blockIdx.y * 32;
    int tx = threadIdx.x, ty = threadIdx.y;   // 32 x 8
#pragma unroll
    for (int i = 0; i < 32; i += 8)
        tile[ty + i][tx] = src[(size_t)(r0 + ty + i) * C + (c0 + tx)];
    __syncthreads();
#pragma unroll
    for (int i = 0; i < 32; i += 8)
        dst[(size_t)(c0 + ty + i) * R + (r0 + tx)] = f2bf(tile[tx][ty + i]);
}

// =====================================================================
// 256x128-tile bf16 GEMM: C = A(MxK) * Bt(NxK)^T
// r13 mechanism (cross-block overlap, m114/m97) with HALVED step count:
//   * 8 waves (4M x 2N), per-wave 64x64 via 4x4 acc of 16x16x32 MFMA
//     (per-wave regs identical to r13 -> still 4 waves/SIMD; 2 blocks/CU
//      x 8 waves = same 16 waves/CU, but half the block-steps/CU ->
//      half the per-step sync residual; LDS B/FLOP 46 -> 42)
//   * BK=64, SINGLE 48 KB LDS buffer (A 32K @0, B 16K @32768),
//     plain __syncthreads() only (compiler emits drains; other resident
//     block computes during this block's stage/drain)
//   * 2-way-free XOR swizzle (r11-verified), XCD-bijective + bn-fast
// =====================================================================

#define GLOAD(srcp, dstofs)                                                   \
    __builtin_amdgcn_global_load_lds(                                         \
        (__attribute__((address_space(1))) void*)(srcp),                      \
        (__attribute__((address_space(3))) void*)(ldsb + (dstofs)), 16, 0, 0)

template <bool GELU_BF16>
__global__ __launch_bounds__(512, 2)
void gemm256x128_kernel(const short* __restrict__ A, const short* __restrict__ Bt,
                        void* __restrict__ Cout, int M, int N, int K) {
    __shared__ char lds[49152];    // A[256 rows x 128B] @0, B[128 rows x 128B] @32768
    char* ldsb = &lds[0];

    const int tid = threadIdx.x;
    const int w   = tid >> 6;      // 0..7
    const int l   = tid & 63;
    const int wm  = w >> 1;        // 0..3
    const int wn  = w & 1;         // 0..1
    const int kq  = l >> 4;        // 0..3
    const int l15 = l & 15;

    // XCD-bijective block swizzle; bn-fast so consecutive blocks share the A-tile
    const int nwg = gridDim.x;
    int swzw = blockIdx.x;
    if ((nwg & 7) == 0) swzw = (swzw & 7) * (nwg >> 3) + (swzw >> 3);
    const int NB = N >> 7;
    const int bm = swzw / NB, bn = swzw % NB;
    const int m0 = bm << 8, n0 = bn << 7;

    // ---- swizzled ds_read byte offsets, ks=0 (ks=1: off ^ 0x40) ----
    int offA[4], offB[4];
#pragma unroll
    for (int mi = 0; mi < 4; ++mi) {
        const int r = wm * 64 + mi * 16 + l15;           // 0..255
        offA[mi] = r * 128 + ((kq ^ (r & 7)) << 4);
    }
#pragma unroll
    for (int ni = 0; ni < 4; ++ni) {
        const int r = wn * 64 + ni * 16 + l15;           // 0..127
        offB[ni] = 32768 + r * 128 + ((kq ^ (r & 7)) << 4);
    }

    // ---- staging sources (inverse-swizzled global, linear LDS dest) ----
    // sweep j: X = j*8192 + tid*16 ; P = X ^ (((X>>7)&7)<<4) ;
    // row = P>>7, col elems = (P&127)>>1
    const short *gA[4], *gB[2];
#pragma unroll
    for (int j = 0; j < 4; ++j) {
        const int X = j * 8192 + tid * 16;
        const int P = X ^ (((X >> 7) & 7) << 4);
        const int r = P >> 7, c = (P & 127) >> 1;
        gA[j] = A + (size_t)(m0 + r) * K + c;
    }
#pragma unroll
    for (int j = 0; j < 2; ++j) {
        const int X = j * 8192 + tid * 16;
        const int P = X ^ (((X >> 7) & 7) << 4);
        const int r = P >> 7, c = (P & 127) >> 1;
        gB[j] = Bt + (size_t)(n0 + r) * K + c;
    }

    f32x4 acc[4][4];
#pragma unroll
    for (int mi = 0; mi < 4; ++mi)
#pragma unroll
        for (int ni = 0; ni < 4; ++ni)
            acc[mi][ni] = (f32x4){0.f, 0.f, 0.f, 0.f};

    const int NT = K >> 6;         // K-steps of 64 (16 or 64 here)

    for (int t = 0; t < NT; ++t) {
        __syncthreads();           // WAR: previous step's reads done
#pragma unroll
        for (int j = 0; j < 4; ++j)
            GLOAD(gA[j] + (size_t)t * 64,         j * 8192 + tid * 16);
#pragma unroll
        for (int j = 0; j < 2; ++j)
            GLOAD(gB[j] + (size_t)t * 64, 32768 + j * 8192 + tid * 16);
        __syncthreads();           // compiler drains vmcnt before barrier
#pragma unroll
        for (int ks = 0; ks < 2; ++ks) {
            bf16x8 a[4], b[4];
#pragma unroll
            for (int mi = 0; mi < 4; ++mi)
                a[mi] = *reinterpret_cast<const bf16x8*>(ldsb + (offA[mi] ^ (ks << 6)));
#pragma unroll
            for (int ni = 0; ni < 4; ++ni)
                b[ni] = *reinterpret_cast<const bf16x8*>(ldsb + (offB[ni] ^ (ks << 6)));
#pragma unroll
            for (int mi = 0; mi < 4; ++mi)
#pragma unroll
                for (int ni = 0; ni < 4; ++ni)
                    acc[mi][ni] = __builtin_amdgcn_mfma_f32_16x16x32_bf16(
                        a[mi], b[ni], acc[mi][ni], 0, 0, 0);
        }
    }

    // epilogue — D layout (m89): col = lane&15, row = (lane>>4)*4 + reg
    const int row_base = m0 + wm * 64 + kq * 4;
    const int col_base = n0 + wn * 64 + l15;
    if constexpr (GELU_BF16) {
        short* C = reinterpret_cast<short*>(Cout);
#pragma unroll
        for (int mi = 0; mi < 4; ++mi)
#pragma unroll
            for (int r = 0; r < 4; ++r) {
                const size_t ro = (size_t)(row_base + mi * 16 + r) * N;
#pragma unroll
                for (int ni = 0; ni < 4; ++ni) {
                    float x = acc[mi][ni][r];
                    float u = 0.7978845608028654f * (x + 0.044715f * x * x * x);
                    float g = x / (1.f + __expf(-2.f * u));
                    C[ro + col_base + ni * 16] = f2bf(g);
                }
            }
    } else {
        float* C = reinterpret_cast<float*>(Cout);
#pragma unroll
        for (int mi = 0; mi < 4; ++mi)
#pragma unroll
            for (int r = 0; r < 4; ++r) {
                const size_t ro = (size_t)(row_base + mi * 16 + r) * N;
#pragma unroll
                for (int ni = 0; ni < 4; ++ni)
                    C[ro + col_base + ni * 16] = acc[mi][ni][r];
            }
    }
}

// ---------------- intervention: out[b, eot[b], 0:512] = row[0:512] @ Wrot @ Winv ----------------
__global__ void intervention_kernel(const float* __restrict__ Wrot, const float* __restrict__ Winv,
                                    const int* __restrict__ eot, float* __restrict__ out) {
    __shared__ float tgt[DT_SZ];
    __shared__ float tmp[DT_SZ];
    const int b = blockIdx.x;
    const int j = threadIdx.x;
    float* row = out + ((size_t)b * S_SZ + eot[b]) * D_SZ;
    tgt[j] = row[j];                      // ST=0 slice
    __syncthreads();
    float s = 0.f;
#pragma unroll 8
    for (int i = 0; i < DT_SZ; ++i) s = fmaf(tgt[i], Wrot[(size_t)i * DT_SZ + j], s);
    tmp[j] = s;
    __syncthreads();
    float s2 = 0.f;
#pragma unroll 8
    for (int i = 0; i < DT_SZ; ++i) s2 = fmaf(tmp[i], Winv[(size_t)i * DT_SZ + j], s2);
    row[j] = s2;
}

extern "C" void kernel_launch(void* const* d_in, const int* in_sizes, int n_in,
                              void* d_out, int out_size, void* d_ws, size_t ws_size,
                              hipStream_t stream) {
    const float* hidden = (const float*)d_in[0];
    const float* W1     = (const float*)d_in[1];
    const float* W2     = (const float*)d_in[2];
    const float* Wrot   = (const float*)d_in[3];
    const float* Winv   = (const float*)d_in[4];
    const int*   eot    = (const int*)d_in[5];
    float* out = (float*)d_out;

    const int M = B_SZ * S_SZ;   // 32768

    // ws layout: W1t (FF x D bf16) | W2t (D x FF bf16) | Xbf chunk | C1 chunk
    short* W1t = (short*)d_ws;
    short* W2t = W1t + (size_t)FF_SZ * D_SZ;
    short* Xbf = W2t + (size_t)FF_SZ * D_SZ;
    const size_t fixed_bytes = 2ull * (size_t)FF_SZ * D_SZ * sizeof(short);  // 16 MiB
    const size_t per_row = (size_t)D_SZ * 2 + (size_t)FF_SZ * 2;             // 10240 B
    size_t rem = ws_size > fixed_bytes ? ws_size - fixed_bytes : 0;
    int Mc = (int)(rem / per_row);
    Mc = (Mc / 512) * 512;       // keeps every grid a multiple of 8
    if (Mc < 512) Mc = 512;
    if (Mc > M) Mc = M;
    short* C1 = Xbf + (size_t)Mc * D_SZ;

    transpose_cast_kernel<<<dim3(FF_SZ / 32, D_SZ / 32), dim3(32, 8), 0, stream>>>(W1, W1t, D_SZ, FF_SZ);
    transpose_cast_kernel<<<dim3(D_SZ / 32, FF_SZ / 32), dim3(32, 8), 0, stream>>>(W2, W2t, FF_SZ, D_SZ);

    for (int ms = 0; ms < M; ms += Mc) {
        const int mc = (M - ms < Mc) ? (M - ms) : Mc;   // multiple of 512
        const int n8 = mc * D_SZ / 8;
        cast_x_kernel<<<(n8 + 255) / 256, 256, 0, stream>>>(hidden + (size_t)ms * D_SZ, Xbf, n8);
        gemm256x128_kernel<true ><<<dim3((mc / 256) * (FF_SZ / 128)), 512, 0, stream>>>(
            Xbf, W1t, C1, mc, FF_SZ, D_SZ);
        gemm256x128_kernel<false><<<dim3((mc / 256) * (D_SZ / 128)), 512, 0, stream>>>(
            C1, W2t, out + (size_t)ms * D_SZ, mc, D_SZ, FF_SZ);
    }
    intervention_kernel<<<B_SZ, DT_SZ, 0, stream>>>(Wrot, Winv, eot, out);
}